// Round 5
// baseline (686.380 us; speedup 1.0000x reference)
//
#include <hip/hip_runtime.h>
#include <hip/hip_fp16.h>

#define DIN 512
#define DHID 128
#define DOUT 4
#define BSH 8                 // bucket = 256 nodes
#define PA_CHUNK 8192         // edges per binning block (32/thread)

typedef _Float16 f16x8 __attribute__((ext_vector_type(8)));
typedef _Float16 f16x4 __attribute__((ext_vector_type(4)));
typedef float    f32x4 __attribute__((ext_vector_type(4)));

// ---------- edge dtype detection (int64 vs int32 ABI) ----------
__global__ void detect_i64_k(const int* __restrict__ raw, int* __restrict__ flag) {
  if (blockIdx.x == 0 && threadIdx.x == 0) {
    int z = 1;
    for (int k = 0; k < 8; ++k)
      if (raw[2 * k + 1] != 0) z = 0;
    flag[0] = z;
  }
}

// ---------- bucket histogram (391 buckets) via LDS ----------
__global__ __launch_bounds__(256) void bcount_k(const int* __restrict__ raw,
                                                const int* __restrict__ flag,
                                                int* __restrict__ gbcnt, int E) {
  __shared__ int h[512];
  const int tid = threadIdx.x;
  const int f = flag[0];
  for (int i = tid; i < 512; i += 256) h[i] = 0;
  __syncthreads();
  const size_t e0 = (size_t)blockIdx.x * PA_CHUNK;
  #pragma unroll
  for (int k = 0; k < 32; ++k) {
    size_t e = e0 + (size_t)k * 256 + tid;
    if (e < (size_t)E) {
      int d = f ? raw[2 * ((size_t)E + e)] : raw[(size_t)E + e];
      atomicAdd(&h[d >> BSH], 1);
    }
  }
  __syncthreads();
  for (int i = tid; i < 512; i += 256)
    if (h[i]) atomicAdd(&gbcnt[i], h[i]);
}

// ---------- bucket scan (single block) -> boffs, bcur; also offs[N]=E ----------
__global__ __launch_bounds__(512) void bscan_k(const int* __restrict__ gbcnt,
                                               int* __restrict__ boffs,
                                               int* __restrict__ bcur,
                                               int* __restrict__ offs,
                                               int nbkt, int N, int E) {
  __shared__ int sm[512];
  int t = threadIdx.x;
  int v = (t < nbkt) ? gbcnt[t] : 0;
  int x = v;
  sm[t] = x;
  __syncthreads();
  #pragma unroll
  for (int o = 1; o < 512; o <<= 1) {
    int y = (t >= o) ? sm[t - o] : 0;
    __syncthreads();
    x += y;
    sm[t] = x;
    __syncthreads();
  }
  if (t < nbkt) {
    boffs[t] = x - v;
    bcur[t] = x - v;
  }
  if (t == 0) {
    boffs[nbkt] = E;
    offs[N] = E;
  }
}

// ---------- binA: scatter packed (src<<8 | dst&255) into dst-bucket order ----
__global__ __launch_bounds__(256) void binA_k(const int* __restrict__ raw,
                                              const int* __restrict__ flag,
                                              int* __restrict__ bcur,
                                              unsigned* __restrict__ pairs, int E) {
  __shared__ int hist[512];
  __shared__ int base[512];
  const int tid = threadIdx.x;
  const int f = flag[0];
  const size_t e0 = (size_t)blockIdx.x * PA_CHUNK;
  for (int i = tid; i < 512; i += 256) hist[i] = 0;
  __syncthreads();
  int es[32], ed[32];
  #pragma unroll
  for (int k = 0; k < 32; ++k) {
    size_t e = e0 + (size_t)k * 256 + tid;
    if (e < (size_t)E) {
      es[k] = f ? raw[2 * e] : raw[e];
      ed[k] = f ? raw[2 * ((size_t)E + e)] : raw[(size_t)E + e];
      atomicAdd(&hist[ed[k] >> BSH], 1);
    } else {
      ed[k] = -1;
    }
  }
  __syncthreads();
  for (int i = tid; i < 512; i += 256) {
    int c = hist[i];
    base[i] = c ? atomicAdd(&bcur[i], c) : 0;
    hist[i] = 0;  // reuse as local cursor
  }
  __syncthreads();
  #pragma unroll
  for (int k = 0; k < 32; ++k) {
    if (ed[k] >= 0) {
      int b = ed[k] >> BSH;
      int pos = base[b] + atomicAdd(&hist[b], 1);
      pairs[pos] = ((unsigned)es[k] << 8) | ((unsigned)ed[k] & 255u);
    }
  }
}

// ---------- binB: per-bucket local count + scan -> offs/dis, then CSR fill ----
__global__ __launch_bounds__(256) void binB_k(const unsigned* __restrict__ pairs,
                                              const int* __restrict__ boffs,
                                              int* __restrict__ csr,
                                              int* __restrict__ offs,
                                              float* __restrict__ dis, int N) {
  __shared__ int lcnt[256];
  __shared__ int sc[256];
  const int tid = threadIdx.x;
  const int n0 = blockIdx.x << BSH;
  const int lo = boffs[blockIdx.x];
  const int hi = boffs[blockIdx.x + 1];
  lcnt[tid] = 0;
  __syncthreads();
  for (int j = lo + tid; j < hi; j += 256) atomicAdd(&lcnt[(int)(pairs[j] & 255u)], 1);
  __syncthreads();
  int v = lcnt[tid];
  int x = v;
  sc[tid] = x;
  __syncthreads();
  #pragma unroll
  for (int o = 1; o < 256; o <<= 1) {
    int y = (tid >= o) ? sc[tid - o] : 0;
    __syncthreads();
    x += y;
    sc[tid] = x;
    __syncthreads();
  }
  const int base = lo + x - v;   // node's CSR start
  const int node = n0 + tid;
  if (node < N) {
    offs[node] = base;
    dis[node] = rsqrtf((float)v + 1.0f);   // deg = in-degree + self-loop
  }
  __syncthreads();
  lcnt[tid] = base;   // reuse as cursor
  __syncthreads();
  for (int j = lo + tid; j < hi; j += 256) {
    unsigned p = pairs[j];
    int dl = (int)(p & 255u);
    int pos = atomicAdd(&lcnt[dl], 1);
    csr[pos] = (int)(p >> 8);   // lands in this bucket's span -> L2 absorbs
  }
}

// ---------- W1 split to fp16 hi/lo, transposed [128][512] ----------
__global__ __launch_bounds__(256) void wsplit_k(const float* __restrict__ W1,
                                                __half* __restrict__ Wth,
                                                __half* __restrict__ Wtl) {
  int idx = blockIdx.x * 256 + threadIdx.x;   // 0..65535
  if (idx >= DIN * DHID) return;
  int k = idx >> 7;    // 0..511
  int n = idx & 127;
  float w = W1[idx];   // W1[k][n], coalesced read
  _Float16 hi = (_Float16)w;
  _Float16 lo = (_Float16)(w - (float)hi);
  Wth[(size_t)n * DIN + k] = *(__half*)&hi;
  Wtl[(size_t)n * DIN + k] = *(__half*)&lo;
}

// ---------- GEMM1 via split-fp16 MFMA: hs = fp16((X@W1) * dis) ----------
// Barrier-free main loop: each wave owns an independent 32x128 output strip
// and loads A/B MFMA fragments DIRECTLY into registers (no LDS staging, no
// per-K-step __syncthreads convoy). A (HBM-streamed) has a 1-deep named-reg
// prefetch; B (256KB hi+lo) is L1/L2-resident. LDS used only for the
// store-shuffle epilogue.
#define CVT8(vA, vB, hi8, lo8)                                                 \
  {                                                                            \
    _Float16 c0 = (_Float16)(vA).x, c1 = (_Float16)(vA).y,                     \
             c2 = (_Float16)(vA).z, c3 = (_Float16)(vA).w,                     \
             c4 = (_Float16)(vB).x, c5 = (_Float16)(vB).y,                     \
             c6 = (_Float16)(vB).z, c7 = (_Float16)(vB).w;                     \
    hi8 = (f16x8){c0, c1, c2, c3, c4, c5, c6, c7};                             \
    lo8 = (f16x8){(_Float16)((vA).x - (float)c0), (_Float16)((vA).y - (float)c1), \
                  (_Float16)((vA).z - (float)c2), (_Float16)((vA).w - (float)c3), \
                  (_Float16)((vB).x - (float)c4), (_Float16)((vB).y - (float)c5), \
                  (_Float16)((vB).z - (float)c6), (_Float16)((vB).w - (float)c7)};\
  }

__global__ __launch_bounds__(256, 3) void gemm1_k(const float* __restrict__ A,
                                                  const __half* __restrict__ Bth,
                                                  const __half* __restrict__ Btl,
                                                  const float* __restrict__ dis,
                                                  __half* __restrict__ hs, int N) {
  __shared__ _Float16 smem[128 * 136];   // epilogue store-shuffle only (34816B)
  const int tid = threadIdx.x;
  const int wave = tid >> 6, lane = tid & 63;
  const int lr = lane & 15, quad = lane >> 4;
  const int m0 = blockIdx.x * 128;
  const int r0 = m0 + wave * 32 + lr;   // mt=0 fragment row
  const int r1 = r0 + 16;               // mt=1 fragment row

  // fragment pointers: lane holds A[row][k0+quad*8 .. +7] (8 fp32 = 2 float4)
  const float* a0p = A + (size_t)r0 * DIN + quad * 8;
  const float* a1p = A + (size_t)r1 * DIN + quad * 8;
  // B^T fragment: lane holds Bt[c = j*16+lr][k0+quad*8 .. +7] (f16x8, 16B)
  const __half* bhp = Bth + (size_t)lr * DIN + quad * 8;
  const __half* blp = Btl + (size_t)lr * DIN + quad * 8;

  f32x4 acc[2][8];
  #pragma unroll
  for (int mt = 0; mt < 2; ++mt)
    #pragma unroll
    for (int j = 0; j < 8; ++j) acc[mt][j] = (f32x4){0.f, 0.f, 0.f, 0.f};

  const float4 z4 = make_float4(0.f, 0.f, 0.f, 0.f);
  const bool v0 = (r0 < N), v1 = (r1 < N);
  // prologue: A prefetch for k0 = 0
  float4 pa00 = v0 ? *(const float4*)(a0p)     : z4;
  float4 pa01 = v0 ? *(const float4*)(a0p + 4) : z4;
  float4 pa10 = v1 ? *(const float4*)(a1p)     : z4;
  float4 pa11 = v1 ? *(const float4*)(a1p + 4) : z4;

  for (int k0 = 0; k0 < DIN; k0 += 32) {
    // convert current A fragments (register-only)
    f16x8 ah0, al0, ah1, al1;
    CVT8(pa00, pa01, ah0, al0);
    CVT8(pa10, pa11, ah1, al1);
    // issue next K-step A loads; they drain under the MFMA stream below
    if (k0 + 32 < DIN) {
      const int k1 = k0 + 32;
      pa00 = v0 ? *(const float4*)(a0p + k1)     : z4;
      pa01 = v0 ? *(const float4*)(a0p + k1 + 4) : z4;
      pa10 = v1 ? *(const float4*)(a1p + k1)     : z4;
      pa11 = v1 ? *(const float4*)(a1p + k1 + 4) : z4;
    }
    // B in two half-tiles to bound register liveness
    #pragma unroll
    for (int h = 0; h < 2; ++h) {
      f16x8 bh[4], bl[4];
      #pragma unroll
      for (int nt = 0; nt < 4; ++nt) {
        const size_t co = (size_t)(h * 4 + nt) * 16 * DIN + k0;
        bh[nt] = *(const f16x8*)(bhp + co);
        bl[nt] = *(const f16x8*)(blp + co);
      }
      #pragma unroll
      for (int nt = 0; nt < 4; ++nt) {
        const int j = h * 4 + nt;
        acc[0][j] = __builtin_amdgcn_mfma_f32_16x16x32_f16(al0, bh[nt], acc[0][j], 0, 0, 0);
        acc[0][j] = __builtin_amdgcn_mfma_f32_16x16x32_f16(ah0, bl[nt], acc[0][j], 0, 0, 0);
        acc[0][j] = __builtin_amdgcn_mfma_f32_16x16x32_f16(ah0, bh[nt], acc[0][j], 0, 0, 0);
        acc[1][j] = __builtin_amdgcn_mfma_f32_16x16x32_f16(al1, bh[nt], acc[1][j], 0, 0, 0);
        acc[1][j] = __builtin_amdgcn_mfma_f32_16x16x32_f16(ah1, bl[nt], acc[1][j], 0, 0, 0);
        acc[1][j] = __builtin_amdgcn_mfma_f32_16x16x32_f16(ah1, bh[nt], acc[1][j], 0, 0, 0);
      }
    }
  }
  // epilogue: scale by dis, fp16 round via LDS [128][136], coalesced store
  #pragma unroll
  for (int mt = 0; mt < 2; ++mt) {
    #pragma unroll
    for (int r = 0; r < 4; ++r) {
      int row = wave * 32 + mt * 16 + quad * 4 + r;
      int gr = m0 + row;
      float dv = dis[gr < N ? gr : (N - 1)];
      #pragma unroll
      for (int j = 0; j < 8; ++j) {
        int col = j * 16 + lr;
        smem[row * 136 + col] = (_Float16)(acc[mt][j][r] * dv);
      }
    }
  }
  __syncthreads();
  #pragma unroll
  for (int l = 0; l < 8; ++l) {
    int idx = l * 256 + tid;
    int row = idx >> 4;
    int c = (idx & 15) << 3;
    int gr = m0 + row;
    if (gr < N)
      *(uint4*)(hs + (size_t)gr * DHID + c) = *(uint4*)&smem[row * 136 + c];
  }
}

// ---------- fused agg1, unroll-8 gather for memory-level parallelism ----------
__global__ __launch_bounds__(256) void agg1_k(const __half* __restrict__ hs,
                                              const float* __restrict__ dis,
                                              const int* __restrict__ offs,
                                              const int* __restrict__ csr,
                                              const float* __restrict__ W2,
                                              const float* __restrict__ b1,
                                              float* __restrict__ gs, int N) {
  const int wid = threadIdx.x >> 6;
  const int lane = threadIdx.x & 63;
  const int i = blockIdx.x * 4 + wid;
  if (i >= N) return;
  const int f = lane * 2;
  const __half* hp = hs + f;   // lane-fixed column base
  float ax = 0.f, ay = 0.f;
  const int beg = offs[i], end = offs[i + 1];
  for (int base = beg; base < end; base += 64) {
    int sj = 0;
    if (base + lane < end) sj = csr[base + lane];  // coalesced edge-id load
    const int n = min(64, end - base);
    int t = 0;
    for (; t + 8 <= n; t += 8) {   // 8 independent gathers in flight
      int s0 = __shfl(sj, t + 0, 64), s1 = __shfl(sj, t + 1, 64);
      int s2 = __shfl(sj, t + 2, 64), s3 = __shfl(sj, t + 3, 64);
      int s4 = __shfl(sj, t + 4, 64), s5 = __shfl(sj, t + 5, 64);
      int s6 = __shfl(sj, t + 6, 64), s7 = __shfl(sj, t + 7, 64);
      __half2 h0 = *(const __half2*)(hp + (size_t)s0 * DHID);
      __half2 h1 = *(const __half2*)(hp + (size_t)s1 * DHID);
      __half2 h2 = *(const __half2*)(hp + (size_t)s2 * DHID);
      __half2 h3 = *(const __half2*)(hp + (size_t)s3 * DHID);
      __half2 h4 = *(const __half2*)(hp + (size_t)s4 * DHID);
      __half2 h5 = *(const __half2*)(hp + (size_t)s5 * DHID);
      __half2 h6 = *(const __half2*)(hp + (size_t)s6 * DHID);
      __half2 h7 = *(const __half2*)(hp + (size_t)s7 * DHID);
      float2 f0 = __half22float2(h0), f1 = __half22float2(h1);
      float2 f2 = __half22float2(h2), f3 = __half22float2(h3);
      float2 f4 = __half22float2(h4), f5 = __half22float2(h5);
      float2 f6 = __half22float2(h6), f7 = __half22float2(h7);
      ax += ((f0.x + f1.x) + (f2.x + f3.x)) + ((f4.x + f5.x) + (f6.x + f7.x));
      ay += ((f0.y + f1.y) + (f2.y + f3.y)) + ((f4.y + f5.y) + (f6.y + f7.y));
    }
    for (; t < n; ++t) {
      int s = __shfl(sj, t, 64);
      float2 hf = __half22float2(*(const __half2*)(hp + (size_t)s * DHID));
      ax += hf.x;
      ay += hf.y;
    }
  }
  {  // self-loop
    float2 hf = __half22float2(*(const __half2*)(hp + (size_t)i * DHID));
    ax += hf.x;
    ay += hf.y;
  }
  const float di = dis[i];
  float v0 = fmaxf(fmaf(ax, di, b1[f]), 0.f);
  float v1 = fmaxf(fmaf(ay, di, b1[f + 1]), 0.f);
  float p0 = fmaf(v0, W2[f * 4 + 0], v1 * W2[f * 4 + 4]);
  float p1 = fmaf(v0, W2[f * 4 + 1], v1 * W2[f * 4 + 5]);
  float p2 = fmaf(v0, W2[f * 4 + 2], v1 * W2[f * 4 + 6]);
  float p3 = fmaf(v0, W2[f * 4 + 3], v1 * W2[f * 4 + 7]);
  #pragma unroll
  for (int o = 32; o > 0; o >>= 1) {
    p0 += __shfl_xor(p0, o, 64);
    p1 += __shfl_xor(p1, o, 64);
    p2 += __shfl_xor(p2, o, 64);
    p3 += __shfl_xor(p3, o, 64);
  }
  if (lane == 0)
    *(float4*)(gs + (size_t)i * DOUT) = make_float4(p0 * di, p1 * di, p2 * di, p3 * di);
}

// ---------- layer-2: out = dis_i*(sum gs[s] + gs[i]) + b2, unroll-4 ----------
__global__ __launch_bounds__(256) void agg2_k(const float* __restrict__ gs,
                                              const float* __restrict__ dis,
                                              const int* __restrict__ offs,
                                              const int* __restrict__ csr,
                                              const float* __restrict__ b2,
                                              float* __restrict__ out, int N) {
  int i = blockIdx.x * 256 + threadIdx.x;
  if (i >= N) return;
  float a0 = 0.f, a1 = 0.f, a2 = 0.f, a3 = 0.f;
  const int beg = offs[i], end = offs[i + 1];
  int j = beg;
  for (; j + 4 <= end; j += 4) {
    int s0 = csr[j], s1 = csr[j + 1], s2 = csr[j + 2], s3 = csr[j + 3];
    float4 g0 = *(const float4*)(gs + (size_t)s0 * DOUT);
    float4 g1 = *(const float4*)(gs + (size_t)s1 * DOUT);
    float4 g2 = *(const float4*)(gs + (size_t)s2 * DOUT);
    float4 g3 = *(const float4*)(gs + (size_t)s3 * DOUT);
    a0 += (g0.x + g1.x) + (g2.x + g3.x);
    a1 += (g0.y + g1.y) + (g2.y + g3.y);
    a2 += (g0.z + g1.z) + (g2.z + g3.z);
    a3 += (g0.w + g1.w) + (g2.w + g3.w);
  }
  for (; j < end; ++j) {
    int s = csr[j];
    float4 gv = *(const float4*)(gs + (size_t)s * DOUT);
    a0 += gv.x; a1 += gv.y; a2 += gv.z; a3 += gv.w;
  }
  const float di = dis[i];
  float4 gi = *(const float4*)(gs + (size_t)i * DOUT);
  float4 o4;
  o4.x = fmaf(a0 + gi.x, di, b2[0]);
  o4.y = fmaf(a1 + gi.y, di, b2[1]);
  o4.z = fmaf(a2 + gi.z, di, b2[2]);
  o4.w = fmaf(a3 + gi.w, di, b2[3]);
  *(float4*)(out + (size_t)i * DOUT) = o4;
}

extern "C" void kernel_launch(void* const* d_in, const int* in_sizes, int n_in,
                              void* d_out, int out_size, void* d_ws, size_t ws_size,
                              hipStream_t stream) {
  const float* x  = (const float*)d_in[0];
  const int*   raw = (const int*)d_in[1];
  const float* W1 = (const float*)d_in[2];
  const float* b1 = (const float*)d_in[3];
  const float* W2 = (const float*)d_in[4];
  const float* b2 = (const float*)d_in[5];
  float* out = (float*)d_out;

  const int N = in_sizes[0] / DIN;   // 100000
  const int E = in_sizes[1] / 2;     // 3200000

  char* ws = (char*)d_ws;
  size_t off = 0;
  auto carve = [&](size_t bytes) -> char* {
    char* p = ws + off;
    off = (off + bytes + 255) & ~(size_t)255;
    return p;
  };
  float*    dis  = (float*)carve((size_t)N * 4);
  int*      offs = (int*)carve((size_t)(N + 1) * 4);
  int*      csr  = (int*)carve((size_t)E * 4);
  unsigned* pairs= (unsigned*)carve((size_t)E * 4);
  int*      boffs= (int*)carve(513 * 4);
  int*      bcur = (int*)carve(512 * 4);
  int*      gbcnt= (int*)carve(512 * 4);
  int*      flag = (int*)carve(256);
  __half*   Wth  = (__half*)carve((size_t)DIN * DHID * 2);
  __half*   Wtl  = (__half*)carve((size_t)DIN * DHID * 2);
  __half*   hs   = (__half*)carve((size_t)N * DHID * 2);
  float*    gs   = (float*)carve((size_t)N * DOUT * 4);
  (void)ws_size; (void)n_in; (void)out_size;

  const int gN = (N + 255) / 256;
  const int nbkt = (N + (1 << BSH) - 1) >> BSH;   // 391
  const int gA = (E + PA_CHUNK - 1) / PA_CHUNK;   // 391

  detect_i64_k<<<1, 64, 0, stream>>>(raw, flag);
  hipMemsetAsync(gbcnt, 0, 512 * 4, stream);
  bcount_k<<<gA, 256, 0, stream>>>(raw, flag, gbcnt, E);
  bscan_k<<<1, 512, 0, stream>>>(gbcnt, boffs, bcur, offs, nbkt, N, E);
  binA_k<<<gA, 256, 0, stream>>>(raw, flag, bcur, pairs, E);
  binB_k<<<nbkt, 256, 0, stream>>>(pairs, boffs, csr, offs, dis, N);
  wsplit_k<<<(DIN * DHID + 255) / 256, 256, 0, stream>>>(W1, Wth, Wtl);
  gemm1_k<<<(N + 127) / 128, 256, 0, stream>>>(x, Wth, Wtl, dis, hs, N);
  agg1_k<<<(N + 3) / 4, 256, 0, stream>>>(hs, dis, offs, csr, W2, b1, gs, N);
  agg2_k<<<gN, 256, 0, stream>>>(gs, dis, offs, csr, b2, out, N);
}

// Round 6
// 535.301 us; speedup vs baseline: 1.2822x; 1.2822x over previous
//
#include <hip/hip_runtime.h>
#include <hip/hip_fp16.h>

#define DIN 512
#define DHID 128
#define DOUT 4
#define BSH 8                 // bucket = 256 nodes
#define PA_CHUNK 8192         // edges per binning block (32/thread)

typedef _Float16 f16x8 __attribute__((ext_vector_type(8)));
typedef _Float16 f16x4 __attribute__((ext_vector_type(4)));
typedef float    f32x4 __attribute__((ext_vector_type(4)));

// async global->LDS DMA, 16B per lane (dest = wave-uniform base + lane*16)
#define GLOAD_LDS(gp, lp)                                                     \
  __builtin_amdgcn_global_load_lds(                                           \
      (const __attribute__((address_space(1))) void*)(gp),                    \
      (__attribute__((address_space(3))) void*)(lp), 16, 0, 0)

// ---------- edge dtype detection (int64 vs int32 ABI) ----------
__global__ void detect_i64_k(const int* __restrict__ raw, int* __restrict__ flag) {
  if (blockIdx.x == 0 && threadIdx.x == 0) {
    int z = 1;
    for (int k = 0; k < 8; ++k)
      if (raw[2 * k + 1] != 0) z = 0;
    flag[0] = z;
  }
}

// ---------- bucket histogram (391 buckets) via LDS ----------
__global__ __launch_bounds__(256) void bcount_k(const int* __restrict__ raw,
                                                const int* __restrict__ flag,
                                                int* __restrict__ gbcnt, int E) {
  __shared__ int h[512];
  const int tid = threadIdx.x;
  const int f = flag[0];
  for (int i = tid; i < 512; i += 256) h[i] = 0;
  __syncthreads();
  const size_t e0 = (size_t)blockIdx.x * PA_CHUNK;
  #pragma unroll
  for (int k = 0; k < 32; ++k) {
    size_t e = e0 + (size_t)k * 256 + tid;
    if (e < (size_t)E) {
      int d = f ? raw[2 * ((size_t)E + e)] : raw[(size_t)E + e];
      atomicAdd(&h[d >> BSH], 1);
    }
  }
  __syncthreads();
  for (int i = tid; i < 512; i += 256)
    if (h[i]) atomicAdd(&gbcnt[i], h[i]);
}

// ---------- bucket scan (single block) -> boffs, bcur; also offs[N]=E ----------
__global__ __launch_bounds__(512) void bscan_k(const int* __restrict__ gbcnt,
                                               int* __restrict__ boffs,
                                               int* __restrict__ bcur,
                                               int* __restrict__ offs,
                                               int nbkt, int N, int E) {
  __shared__ int sm[512];
  int t = threadIdx.x;
  int v = (t < nbkt) ? gbcnt[t] : 0;
  int x = v;
  sm[t] = x;
  __syncthreads();
  #pragma unroll
  for (int o = 1; o < 512; o <<= 1) {
    int y = (t >= o) ? sm[t - o] : 0;
    __syncthreads();
    x += y;
    sm[t] = x;
    __syncthreads();
  }
  if (t < nbkt) {
    boffs[t] = x - v;
    bcur[t] = x - v;
  }
  if (t == 0) {
    boffs[nbkt] = E;
    offs[N] = E;
  }
}

// ---------- binA: scatter packed (src<<8 | dst&255) into dst-bucket order ----
__global__ __launch_bounds__(256) void binA_k(const int* __restrict__ raw,
                                              const int* __restrict__ flag,
                                              int* __restrict__ bcur,
                                              unsigned* __restrict__ pairs, int E) {
  __shared__ int hist[512];
  __shared__ int base[512];
  const int tid = threadIdx.x;
  const int f = flag[0];
  const size_t e0 = (size_t)blockIdx.x * PA_CHUNK;
  for (int i = tid; i < 512; i += 256) hist[i] = 0;
  __syncthreads();
  int es[32], ed[32];
  #pragma unroll
  for (int k = 0; k < 32; ++k) {
    size_t e = e0 + (size_t)k * 256 + tid;
    if (e < (size_t)E) {
      es[k] = f ? raw[2 * e] : raw[e];
      ed[k] = f ? raw[2 * ((size_t)E + e)] : raw[(size_t)E + e];
      atomicAdd(&hist[ed[k] >> BSH], 1);
    } else {
      ed[k] = -1;
    }
  }
  __syncthreads();
  for (int i = tid; i < 512; i += 256) {
    int c = hist[i];
    base[i] = c ? atomicAdd(&bcur[i], c) : 0;
    hist[i] = 0;  // reuse as local cursor
  }
  __syncthreads();
  #pragma unroll
  for (int k = 0; k < 32; ++k) {
    if (ed[k] >= 0) {
      int b = ed[k] >> BSH;
      int pos = base[b] + atomicAdd(&hist[b], 1);
      pairs[pos] = ((unsigned)es[k] << 8) | ((unsigned)ed[k] & 255u);
    }
  }
}

// ---------- binB: per-bucket local count + scan -> offs/dis, then CSR fill ----
__global__ __launch_bounds__(256) void binB_k(const unsigned* __restrict__ pairs,
                                              const int* __restrict__ boffs,
                                              int* __restrict__ csr,
                                              int* __restrict__ offs,
                                              float* __restrict__ dis, int N) {
  __shared__ int lcnt[256];
  __shared__ int sc[256];
  const int tid = threadIdx.x;
  const int n0 = blockIdx.x << BSH;
  const int lo = boffs[blockIdx.x];
  const int hi = boffs[blockIdx.x + 1];
  lcnt[tid] = 0;
  __syncthreads();
  for (int j = lo + tid; j < hi; j += 256) atomicAdd(&lcnt[(int)(pairs[j] & 255u)], 1);
  __syncthreads();
  int v = lcnt[tid];
  int x = v;
  sc[tid] = x;
  __syncthreads();
  #pragma unroll
  for (int o = 1; o < 256; o <<= 1) {
    int y = (tid >= o) ? sc[tid - o] : 0;
    __syncthreads();
    x += y;
    sc[tid] = x;
    __syncthreads();
  }
  const int base = lo + x - v;   // node's CSR start
  const int node = n0 + tid;
  if (node < N) {
    offs[node] = base;
    dis[node] = rsqrtf((float)v + 1.0f);   // deg = in-degree + self-loop
  }
  __syncthreads();
  lcnt[tid] = base;   // reuse as cursor
  __syncthreads();
  for (int j = lo + tid; j < hi; j += 256) {
    unsigned p = pairs[j];
    int dl = (int)(p & 255u);
    int pos = atomicAdd(&lcnt[dl], 1);
    csr[pos] = (int)(p >> 8);   // lands in this bucket's span -> L2 absorbs
  }
}

// ---------- W1 split to fp16 hi/lo, K-tiled LDS-linear layout ----------
// Bt2[kt][row(n)][ hi kk=0..31 | lo kk=0..31 ]  (row = 128B, LDS-DMA-ready)
__global__ __launch_bounds__(256) void wsplit_k(const float* __restrict__ W1,
                                                __half* __restrict__ Bt2) {
  int idx = blockIdx.x * 256 + threadIdx.x;   // 0..65535
  if (idx >= DIN * DHID) return;
  int k = idx >> 7;    // 0..511
  int n = idx & 127;
  int kt = k >> 5, kk = k & 31;
  float w = W1[idx];   // W1[k][n], coalesced read
  _Float16 hi = (_Float16)w;
  _Float16 lo = (_Float16)(w - (float)hi);
  size_t base = (size_t)(kt * 128 + n) * 64;
  Bt2[base + kk]      = *(__half*)&hi;
  Bt2[base + 32 + kk] = *(__half*)&lo;
}

// ---------- GEMM1 via split-fp16 MFMA: hs = fp16((X@W1) * dis) ----------
// m97-style: async global_load_lds staging (A as raw fp32, B pre-split/tiled),
// XOR-swizzled LDS (inverse-swizzle on the global SOURCE, swizzle on ds_read:
// rule both-sides-or-neither). fp32->hi/lo conversion at fragment-read time,
// register-only, hidden under MFMA. 2 barriers/K-step, no stage-phase VALU.
__global__ __launch_bounds__(256, 4) void gemm1_k(const float* __restrict__ A,
                                                  const __half* __restrict__ Bt2,
                                                  const float* __restrict__ dis,
                                                  __half* __restrict__ hs, int N) {
  __shared__ _Float16 smem[128 * 136];           // 34816 B (also epilogue buffer)
  char* sAc = (char*)smem;                       // A: [128 rows][8 chunks x16B] fp32
  char* sBc = (char*)smem + 16384;               // B: [128 rows][8 chunks x16B] f16 hi|lo
  const int tid = threadIdx.x;
  const int wave = tid >> 6, lane = tid & 63;
  const int lr = lane & 15, quad = lane >> 4;
  const int m0 = blockIdx.x * 128;
  const int mbase = (wave >> 1) * 64;   // wave owns 64x64 of the 128x128 tile
  const int nbase = (wave & 1) * 64;
  const int wbase = (tid & ~63) * 16;   // wave-uniform LDS byte base per issue

  f32x4 acc[4][4];
  #pragma unroll
  for (int mt = 0; mt < 4; ++mt)
    #pragma unroll
    for (int nt = 0; nt < 4; ++nt) acc[mt][nt] = (f32x4){0.f, 0.f, 0.f, 0.f};

  // per-thread staging source geometry (dest16 = l*256 + tid)
  int arow[4], achk[4];
  #pragma unroll
  for (int l = 0; l < 4; ++l) {
    int d16 = l * 256 + tid;
    int row = d16 >> 3;
    arow[l] = row;
    achk[l] = (d16 & 7) ^ (row & 7);   // inverse swizzle on source
  }

  for (int kt = 0; kt < 16; ++kt) {
    const int k0 = kt * 32;
    // ---- stage: 8 async DMA issues, no VALU, no VGPR round-trip ----
    #pragma unroll
    for (int l = 0; l < 4; ++l) {
      int gr = m0 + arow[l];
      if (gr >= N) gr = N - 1;          // clamp: dup data, rows >=N never stored
      GLOAD_LDS(A + (size_t)gr * DIN + k0 + achk[l] * 4,
                sAc + (size_t)l * 4096 + wbase);
    }
    #pragma unroll
    for (int l = 0; l < 4; ++l) {
      GLOAD_LDS(Bt2 + (size_t)(kt * 128 + arow[l]) * 64 + achk[l] * 8,
                sBc + (size_t)l * 4096 + wbase);
    }
    __syncthreads();   // drains vmcnt(0): DMA data visible
    // ---- fragments: swizzled ds_read + in-register fp32->hi/lo split ----
    f16x8 ah[4], al[4];
    #pragma unroll
    for (int mt = 0; mt < 4; ++mt) {
      int r = mbase + mt * 16 + lr;
      f32x4 v0 = *(const f32x4*)(sAc + r * 128 + (((2 * quad + 0) ^ (r & 7)) << 4));
      f32x4 v1 = *(const f32x4*)(sAc + r * 128 + (((2 * quad + 1) ^ (r & 7)) << 4));
      _Float16 c0 = (_Float16)v0[0], c1 = (_Float16)v0[1],
               c2 = (_Float16)v0[2], c3 = (_Float16)v0[3],
               c4 = (_Float16)v1[0], c5 = (_Float16)v1[1],
               c6 = (_Float16)v1[2], c7 = (_Float16)v1[3];
      ah[mt] = (f16x8){c0, c1, c2, c3, c4, c5, c6, c7};
      al[mt] = (f16x8){(_Float16)(v0[0] - (float)c0), (_Float16)(v0[1] - (float)c1),
                       (_Float16)(v0[2] - (float)c2), (_Float16)(v0[3] - (float)c3),
                       (_Float16)(v1[0] - (float)c4), (_Float16)(v1[1] - (float)c5),
                       (_Float16)(v1[2] - (float)c6), (_Float16)(v1[3] - (float)c7)};
    }
    #pragma unroll
    for (int nt = 0; nt < 4; ++nt) {
      int c = nbase + nt * 16 + lr;
      f16x8 bh = *(const f16x8*)(sBc + c * 128 + (((0 + quad) ^ (c & 7)) << 4));
      f16x8 bl = *(const f16x8*)(sBc + c * 128 + (((4 + quad) ^ (c & 7)) << 4));
      #pragma unroll
      for (int mt = 0; mt < 4; ++mt)
        acc[mt][nt] = __builtin_amdgcn_mfma_f32_16x16x32_f16(al[mt], bh, acc[mt][nt], 0, 0, 0);
      #pragma unroll
      for (int mt = 0; mt < 4; ++mt)
        acc[mt][nt] = __builtin_amdgcn_mfma_f32_16x16x32_f16(ah[mt], bl, acc[mt][nt], 0, 0, 0);
      #pragma unroll
      for (int mt = 0; mt < 4; ++mt)
        acc[mt][nt] = __builtin_amdgcn_mfma_f32_16x16x32_f16(ah[mt], bh, acc[mt][nt], 0, 0, 0);
    }
    __syncthreads();   // all reads done before next tile's DMA overwrites
  }
  // epilogue: scale by dis, fp16 round via LDS [128][136], coalesced store
  #pragma unroll
  for (int mt = 0; mt < 4; ++mt) {
    #pragma unroll
    for (int r = 0; r < 4; ++r) {
      int row = mbase + mt * 16 + quad * 4 + r;
      int gr = m0 + row;
      float dv = dis[gr < N ? gr : (N - 1)];
      #pragma unroll
      for (int nt = 0; nt < 4; ++nt) {
        int col = nbase + nt * 16 + lr;
        smem[row * 136 + col] = (_Float16)(acc[mt][nt][r] * dv);
      }
    }
  }
  __syncthreads();
  #pragma unroll
  for (int l = 0; l < 8; ++l) {
    int idx = l * 256 + tid;
    int row = idx >> 4;
    int c = (idx & 15) << 3;
    int gr = m0 + row;
    if (gr < N)
      *(uint4*)(hs + (size_t)gr * DHID + c) = *(uint4*)&smem[row * 136 + c];
  }
}

// ---------- fused agg1, unroll-8 gather for memory-level parallelism ----------
__global__ __launch_bounds__(256) void agg1_k(const __half* __restrict__ hs,
                                              const float* __restrict__ dis,
                                              const int* __restrict__ offs,
                                              const int* __restrict__ csr,
                                              const float* __restrict__ W2,
                                              const float* __restrict__ b1,
                                              float* __restrict__ gs, int N) {
  const int wid = threadIdx.x >> 6;
  const int lane = threadIdx.x & 63;
  const int i = blockIdx.x * 4 + wid;
  if (i >= N) return;
  const int f = lane * 2;
  const __half* hp = hs + f;   // lane-fixed column base
  float ax = 0.f, ay = 0.f;
  const int beg = offs[i], end = offs[i + 1];
  for (int base = beg; base < end; base += 64) {
    int sj = 0;
    if (base + lane < end) sj = csr[base + lane];  // coalesced edge-id load
    const int n = min(64, end - base);
    int t = 0;
    for (; t + 8 <= n; t += 8) {   // 8 independent gathers in flight
      int s0 = __shfl(sj, t + 0, 64), s1 = __shfl(sj, t + 1, 64);
      int s2 = __shfl(sj, t + 2, 64), s3 = __shfl(sj, t + 3, 64);
      int s4 = __shfl(sj, t + 4, 64), s5 = __shfl(sj, t + 5, 64);
      int s6 = __shfl(sj, t + 6, 64), s7 = __shfl(sj, t + 7, 64);
      __half2 h0 = *(const __half2*)(hp + (size_t)s0 * DHID);
      __half2 h1 = *(const __half2*)(hp + (size_t)s1 * DHID);
      __half2 h2 = *(const __half2*)(hp + (size_t)s2 * DHID);
      __half2 h3 = *(const __half2*)(hp + (size_t)s3 * DHID);
      __half2 h4 = *(const __half2*)(hp + (size_t)s4 * DHID);
      __half2 h5 = *(const __half2*)(hp + (size_t)s5 * DHID);
      __half2 h6 = *(const __half2*)(hp + (size_t)s6 * DHID);
      __half2 h7 = *(const __half2*)(hp + (size_t)s7 * DHID);
      float2 f0 = __half22float2(h0), f1 = __half22float2(h1);
      float2 f2 = __half22float2(h2), f3 = __half22float2(h3);
      float2 f4 = __half22float2(h4), f5 = __half22float2(h5);
      float2 f6 = __half22float2(h6), f7 = __half22float2(h7);
      ax += ((f0.x + f1.x) + (f2.x + f3.x)) + ((f4.x + f5.x) + (f6.x + f7.x));
      ay += ((f0.y + f1.y) + (f2.y + f3.y)) + ((f4.y + f5.y) + (f6.y + f7.y));
    }
    for (; t < n; ++t) {
      int s = __shfl(sj, t, 64);
      float2 hf = __half22float2(*(const __half2*)(hp + (size_t)s * DHID));
      ax += hf.x;
      ay += hf.y;
    }
  }
  {  // self-loop
    float2 hf = __half22float2(*(const __half2*)(hp + (size_t)i * DHID));
    ax += hf.x;
    ay += hf.y;
  }
  const float di = dis[i];
  float v0 = fmaxf(fmaf(ax, di, b1[f]), 0.f);
  float v1 = fmaxf(fmaf(ay, di, b1[f + 1]), 0.f);
  float p0 = fmaf(v0, W2[f * 4 + 0], v1 * W2[f * 4 + 4]);
  float p1 = fmaf(v0, W2[f * 4 + 1], v1 * W2[f * 4 + 5]);
  float p2 = fmaf(v0, W2[f * 4 + 2], v1 * W2[f * 4 + 6]);
  float p3 = fmaf(v0, W2[f * 4 + 3], v1 * W2[f * 4 + 7]);
  #pragma unroll
  for (int o = 32; o > 0; o >>= 1) {
    p0 += __shfl_xor(p0, o, 64);
    p1 += __shfl_xor(p1, o, 64);
    p2 += __shfl_xor(p2, o, 64);
    p3 += __shfl_xor(p3, o, 64);
  }
  if (lane == 0)
    *(float4*)(gs + (size_t)i * DOUT) = make_float4(p0 * di, p1 * di, p2 * di, p3 * di);
}

// ---------- layer-2: out = dis_i*(sum gs[s] + gs[i]) + b2, unroll-4 ----------
__global__ __launch_bounds__(256) void agg2_k(const float* __restrict__ gs,
                                              const float* __restrict__ dis,
                                              const int* __restrict__ offs,
                                              const int* __restrict__ csr,
                                              const float* __restrict__ b2,
                                              float* __restrict__ out, int N) {
  int i = blockIdx.x * 256 + threadIdx.x;
  if (i >= N) return;
  float a0 = 0.f, a1 = 0.f, a2 = 0.f, a3 = 0.f;
  const int beg = offs[i], end = offs[i + 1];
  int j = beg;
  for (; j + 4 <= end; j += 4) {
    int s0 = csr[j], s1 = csr[j + 1], s2 = csr[j + 2], s3 = csr[j + 3];
    float4 g0 = *(const float4*)(gs + (size_t)s0 * DOUT);
    float4 g1 = *(const float4*)(gs + (size_t)s1 * DOUT);
    float4 g2 = *(const float4*)(gs + (size_t)s2 * DOUT);
    float4 g3 = *(const float4*)(gs + (size_t)s3 * DOUT);
    a0 += (g0.x + g1.x) + (g2.x + g3.x);
    a1 += (g0.y + g1.y) + (g2.y + g3.y);
    a2 += (g0.z + g1.z) + (g2.z + g3.z);
    a3 += (g0.w + g1.w) + (g2.w + g3.w);
  }
  for (; j < end; ++j) {
    int s = csr[j];
    float4 gv = *(const float4*)(gs + (size_t)s * DOUT);
    a0 += gv.x; a1 += gv.y; a2 += gv.z; a3 += gv.w;
  }
  const float di = dis[i];
  float4 gi = *(const float4*)(gs + (size_t)i * DOUT);
  float4 o4;
  o4.x = fmaf(a0 + gi.x, di, b2[0]);
  o4.y = fmaf(a1 + gi.y, di, b2[1]);
  o4.z = fmaf(a2 + gi.z, di, b2[2]);
  o4.w = fmaf(a3 + gi.w, di, b2[3]);
  *(float4*)(out + (size_t)i * DOUT) = o4;
}

extern "C" void kernel_launch(void* const* d_in, const int* in_sizes, int n_in,
                              void* d_out, int out_size, void* d_ws, size_t ws_size,
                              hipStream_t stream) {
  const float* x  = (const float*)d_in[0];
  const int*   raw = (const int*)d_in[1];
  const float* W1 = (const float*)d_in[2];
  const float* b1 = (const float*)d_in[3];
  const float* W2 = (const float*)d_in[4];
  const float* b2 = (const float*)d_in[5];
  float* out = (float*)d_out;

  const int N = in_sizes[0] / DIN;   // 100000
  const int E = in_sizes[1] / 2;     // 3200000

  char* ws = (char*)d_ws;
  size_t off = 0;
  auto carve = [&](size_t bytes) -> char* {
    char* p = ws + off;
    off = (off + bytes + 255) & ~(size_t)255;
    return p;
  };
  float*    dis  = (float*)carve((size_t)N * 4);
  int*      offs = (int*)carve((size_t)(N + 1) * 4);
  int*      csr  = (int*)carve((size_t)E * 4);
  unsigned* pairs= (unsigned*)carve((size_t)E * 4);
  int*      boffs= (int*)carve(513 * 4);
  int*      bcur = (int*)carve(512 * 4);
  int*      gbcnt= (int*)carve(512 * 4);
  int*      flag = (int*)carve(256);
  __half*   Bt2  = (__half*)carve((size_t)DIN * DHID * 2 * 2);  // hi+lo tiled
  __half*   hs   = (__half*)carve((size_t)N * DHID * 2);
  float*    gs   = (float*)carve((size_t)N * DOUT * 4);
  (void)ws_size; (void)n_in; (void)out_size;

  const int gN = (N + 255) / 256;
  const int nbkt = (N + (1 << BSH) - 1) >> BSH;   // 391
  const int gA = (E + PA_CHUNK - 1) / PA_CHUNK;   // 391

  detect_i64_k<<<1, 64, 0, stream>>>(raw, flag);
  hipMemsetAsync(gbcnt, 0, 512 * 4, stream);
  bcount_k<<<gA, 256, 0, stream>>>(raw, flag, gbcnt, E);
  bscan_k<<<1, 512, 0, stream>>>(gbcnt, boffs, bcur, offs, nbkt, N, E);
  binA_k<<<gA, 256, 0, stream>>>(raw, flag, bcur, pairs, E);
  binB_k<<<nbkt, 256, 0, stream>>>(pairs, boffs, csr, offs, dis, N);
  wsplit_k<<<(DIN * DHID + 255) / 256, 256, 0, stream>>>(W1, Bt2);
  gemm1_k<<<(N + 127) / 128, 256, 0, stream>>>(x, Bt2, dis, hs, N);
  agg1_k<<<(N + 3) / 4, 256, 0, stream>>>(hs, dis, offs, csr, W2, b1, gs, N);
  agg2_k<<<gN, 256, 0, stream>>>(gs, dis, offs, csr, b2, out, N);
}

// Round 8
// 533.134 us; speedup vs baseline: 1.2874x; 1.0041x over previous
//
#include <hip/hip_runtime.h>
#include <hip/hip_fp16.h>

#define DIN 512
#define DHID 128
#define DOUT 4
#define BSH 8                 // bucket = 256 nodes
#define PA_CHUNK 8192         // edges per binning block (32/thread)

typedef _Float16 f16x8 __attribute__((ext_vector_type(8)));
typedef _Float16 f16x4 __attribute__((ext_vector_type(4)));
typedef float    f32x4 __attribute__((ext_vector_type(4)));

// async global->LDS DMA, 16B per lane (dest = wave-uniform base + lane*16)
#define GLOAD_LDS(gp, lp)                                                     \
  __builtin_amdgcn_global_load_lds(                                           \
      (const __attribute__((address_space(1))) void*)(gp),                    \
      (__attribute__((address_space(3))) void*)(lp), 16, 0, 0)

// ---------- edge dtype detection (int64 vs int32 ABI) ----------
__global__ void detect_i64_k(const int* __restrict__ raw, int* __restrict__ flag) {
  if (blockIdx.x == 0 && threadIdx.x == 0) {
    int z = 1;
    for (int k = 0; k < 8; ++k)
      if (raw[2 * k + 1] != 0) z = 0;
    flag[0] = z;
  }
}

// ---------- bucket histogram (391 buckets) via LDS ----------
__global__ __launch_bounds__(256) void bcount_k(const int* __restrict__ raw,
                                                const int* __restrict__ flag,
                                                int* __restrict__ gbcnt, int E) {
  __shared__ int h[512];
  const int tid = threadIdx.x;
  const int f = flag[0];
  for (int i = tid; i < 512; i += 256) h[i] = 0;
  __syncthreads();
  const size_t e0 = (size_t)blockIdx.x * PA_CHUNK;
  #pragma unroll
  for (int k = 0; k < 32; ++k) {
    size_t e = e0 + (size_t)k * 256 + tid;
    if (e < (size_t)E) {
      int d = f ? raw[2 * ((size_t)E + e)] : raw[(size_t)E + e];
      atomicAdd(&h[d >> BSH], 1);
    }
  }
  __syncthreads();
  for (int i = tid; i < 512; i += 256)
    if (h[i]) atomicAdd(&gbcnt[i], h[i]);
}

// ---------- bucket scan (single block) -> boffs, bcur; also offs[N]=E ----------
__global__ __launch_bounds__(512) void bscan_k(const int* __restrict__ gbcnt,
                                               int* __restrict__ boffs,
                                               int* __restrict__ bcur,
                                               int* __restrict__ offs,
                                               int nbkt, int N, int E) {
  __shared__ int sm[512];
  int t = threadIdx.x;
  int v = (t < nbkt) ? gbcnt[t] : 0;
  int x = v;
  sm[t] = x;
  __syncthreads();
  #pragma unroll
  for (int o = 1; o < 512; o <<= 1) {
    int y = (t >= o) ? sm[t - o] : 0;
    __syncthreads();
    x += y;
    sm[t] = x;
    __syncthreads();
  }
  if (t < nbkt) {
    boffs[t] = x - v;
    bcur[t] = x - v;
  }
  if (t == 0) {
    boffs[nbkt] = E;
    offs[N] = E;
  }
}

// ---------- binA: scatter packed (src<<8 | dst&255) into dst-bucket order ----
__global__ __launch_bounds__(256) void binA_k(const int* __restrict__ raw,
                                              const int* __restrict__ flag,
                                              int* __restrict__ bcur,
                                              unsigned* __restrict__ pairs, int E) {
  __shared__ int hist[512];
  __shared__ int base[512];
  const int tid = threadIdx.x;
  const int f = flag[0];
  const size_t e0 = (size_t)blockIdx.x * PA_CHUNK;
  for (int i = tid; i < 512; i += 256) hist[i] = 0;
  __syncthreads();
  int es[32], ed[32];
  #pragma unroll
  for (int k = 0; k < 32; ++k) {
    size_t e = e0 + (size_t)k * 256 + tid;
    if (e < (size_t)E) {
      es[k] = f ? raw[2 * e] : raw[e];
      ed[k] = f ? raw[2 * ((size_t)E + e)] : raw[(size_t)E + e];
      atomicAdd(&hist[ed[k] >> BSH], 1);
    } else {
      ed[k] = -1;
    }
  }
  __syncthreads();
  for (int i = tid; i < 512; i += 256) {
    int c = hist[i];
    base[i] = c ? atomicAdd(&bcur[i], c) : 0;
    hist[i] = 0;  // reuse as local cursor
  }
  __syncthreads();
  #pragma unroll
  for (int k = 0; k < 32; ++k) {
    if (ed[k] >= 0) {
      int b = ed[k] >> BSH;
      int pos = base[b] + atomicAdd(&hist[b], 1);
      pairs[pos] = ((unsigned)es[k] << 8) | ((unsigned)ed[k] & 255u);
    }
  }
}

// ---------- binB: per-bucket local count + scan -> offs/dis, then CSR fill ----
__global__ __launch_bounds__(256) void binB_k(const unsigned* __restrict__ pairs,
                                              const int* __restrict__ boffs,
                                              int* __restrict__ csr,
                                              int* __restrict__ offs,
                                              float* __restrict__ dis, int N) {
  __shared__ int lcnt[256];
  __shared__ int sc[256];
  const int tid = threadIdx.x;
  const int n0 = blockIdx.x << BSH;
  const int lo = boffs[blockIdx.x];
  const int hi = boffs[blockIdx.x + 1];
  lcnt[tid] = 0;
  __syncthreads();
  for (int j = lo + tid; j < hi; j += 256) atomicAdd(&lcnt[(int)(pairs[j] & 255u)], 1);
  __syncthreads();
  int v = lcnt[tid];
  int x = v;
  sc[tid] = x;
  __syncthreads();
  #pragma unroll
  for (int o = 1; o < 256; o <<= 1) {
    int y = (tid >= o) ? sc[tid - o] : 0;
    __syncthreads();
    x += y;
    sc[tid] = x;
    __syncthreads();
  }
  const int base = lo + x - v;   // node's CSR start
  const int node = n0 + tid;
  if (node < N) {
    offs[node] = base;
    dis[node] = rsqrtf((float)v + 1.0f);   // deg = in-degree + self-loop
  }
  __syncthreads();
  lcnt[tid] = base;   // reuse as cursor
  __syncthreads();
  for (int j = lo + tid; j < hi; j += 256) {
    unsigned p = pairs[j];
    int dl = (int)(p & 255u);
    int pos = atomicAdd(&lcnt[dl], 1);
    csr[pos] = (int)(p >> 8);   // lands in this bucket's span -> L2 absorbs
  }
}

// ---------- W1 split to fp16 hi/lo, K-tiled LDS-linear layout ----------
// Bt2[kt][row(n)][ hi kk=0..31 | lo kk=0..31 ]  (row = 128B, LDS-DMA-ready)
__global__ __launch_bounds__(256) void wsplit_k(const float* __restrict__ W1,
                                                __half* __restrict__ Bt2) {
  int idx = blockIdx.x * 256 + threadIdx.x;   // 0..65535
  if (idx >= DIN * DHID) return;
  int k = idx >> 7;    // 0..511
  int n = idx & 127;
  int kt = k >> 5, kk = k & 31;
  float w = W1[idx];   // W1[k][n], coalesced read
  _Float16 hi = (_Float16)w;
  _Float16 lo = (_Float16)(w - (float)hi);
  size_t base = (size_t)(kt * 128 + n) * 64;
  Bt2[base + kk]      = *(__half*)&hi;
  Bt2[base + 32 + kk] = *(__half*)&lo;
}

// ---------- GEMM1 via split-fp16 MFMA: hs = fp16((X@W1) * dis) ----------
// Counted-vmcnt pipeline (T4): A double-buffered via global_load_lds, next
// A-tile issued BEFORE compute and left in flight across the barrier
// (s_waitcnt vmcnt(4), never 0 in steady state). B single-buffered, issued
// post-compute (L2-hot, short exposure). Raw s_barrier (no vmcnt(0) drain).
// All in-loop VMEM is our DMA -> manual vmcnt counts are exact.
__global__ __launch_bounds__(256, 2) void gemm1_k(const float* __restrict__ A,
                                                  const __half* __restrict__ Bt2,
                                                  const float* __restrict__ dis,
                                                  __half* __restrict__ hs, int N) {
  __shared__ char smem[49152];   // Abuf0 16K | Abuf1 16K | Bbuf 16K
  char* const sB = smem + 32768;
  const int tid = threadIdx.x;
  const int wave = tid >> 6, lane = tid & 63;
  const int lr = lane & 15, quad = lane >> 4;
  const int m0 = blockIdx.x * 128;
  const int mbase = (wave >> 1) * 64;   // wave owns 64x64 of the 128x128 tile
  const int nbase = (wave & 1) * 64;
  const int wbase = (tid & ~63) * 16;   // wave-uniform LDS byte base per issue

  f32x4 acc[4][4];
  #pragma unroll
  for (int mt = 0; mt < 4; ++mt)
    #pragma unroll
    for (int nt = 0; nt < 4; ++nt) acc[mt][nt] = (f32x4){0.f, 0.f, 0.f, 0.f};

  // staging source geometry (dest16 = l*256 + tid); inverse swizzle on source
  const float*  agp[4];
  const __half* bgp[4];
  #pragma unroll
  for (int l = 0; l < 4; ++l) {
    int d16 = l * 256 + tid;
    int row = d16 >> 3;
    int chk = (d16 & 7) ^ (row & 7);
    int gr = m0 + row;
    if (gr >= N) gr = N - 1;            // clamp: dup data, rows >=N never stored
    agp[l] = A + (size_t)gr * DIN + chk * 4;
    bgp[l] = Bt2 + (size_t)row * 64 + chk * 8;
  }

  // prologue: stage tile 0 (A -> buf0, B -> sB); stays in flight into kt=0
  #pragma unroll
  for (int l = 0; l < 4; ++l)
    GLOAD_LDS(agp[l], smem + l * 4096 + wbase);
  #pragma unroll
  for (int l = 0; l < 4; ++l)
    GLOAD_LDS(bgp[l], sB + l * 4096 + wbase);

  int cur = 0;
  for (int kt = 0; kt < 16; ++kt) {
    // issue next A-tile into the other buffer; it rides across the barrier
    if (kt < 15) {
      char* dA = smem + (cur ^ 1) * 16384;
      #pragma unroll
      for (int l = 0; l < 4; ++l)
        GLOAD_LDS(agp[l] + (kt + 1) * 32, dA + l * 4096 + wbase);
      asm volatile("s_waitcnt vmcnt(4)" ::: "memory");   // tile kt (A+B) landed
    } else {
      asm volatile("s_waitcnt vmcnt(0)" ::: "memory");   // final drain
    }
    __builtin_amdgcn_s_barrier();        // all waves' tile-kt data visible
    asm volatile("" ::: "memory");
    // ---- compute tile kt: swizzled ds_read + in-register fp32->hi/lo ----
    char* sA = smem + cur * 16384;
    f16x8 ah[4], al[4];
    #pragma unroll
    for (int mt = 0; mt < 4; ++mt) {
      int r = mbase + mt * 16 + lr;
      f32x4 v0 = *(const f32x4*)(sA + r * 128 + (((2 * quad + 0) ^ (r & 7)) << 4));
      f32x4 v1 = *(const f32x4*)(sA + r * 128 + (((2 * quad + 1) ^ (r & 7)) << 4));
      _Float16 c0 = (_Float16)v0[0], c1 = (_Float16)v0[1],
               c2 = (_Float16)v0[2], c3 = (_Float16)v0[3],
               c4 = (_Float16)v1[0], c5 = (_Float16)v1[1],
               c6 = (_Float16)v1[2], c7 = (_Float16)v1[3];
      ah[mt] = (f16x8){c0, c1, c2, c3, c4, c5, c6, c7};
      al[mt] = (f16x8){(_Float16)(v0[0] - (float)c0), (_Float16)(v0[1] - (float)c1),
                       (_Float16)(v0[2] - (float)c2), (_Float16)(v0[3] - (float)c3),
                       (_Float16)(v1[0] - (float)c4), (_Float16)(v1[1] - (float)c5),
                       (_Float16)(v1[2] - (float)c6), (_Float16)(v1[3] - (float)c7)};
    }
    #pragma unroll
    for (int nt = 0; nt < 4; ++nt) {
      int c = nbase + nt * 16 + lr;
      f16x8 bh = *(const f16x8*)(sB + c * 128 + (((0 + quad) ^ (c & 7)) << 4));
      f16x8 bl = *(const f16x8*)(sB + c * 128 + (((4 + quad) ^ (c & 7)) << 4));
      #pragma unroll
      for (int mt = 0; mt < 4; ++mt)
        acc[mt][nt] = __builtin_amdgcn_mfma_f32_16x16x32_f16(al[mt], bh, acc[mt][nt], 0, 0, 0);
      #pragma unroll
      for (int mt = 0; mt < 4; ++mt)
        acc[mt][nt] = __builtin_amdgcn_mfma_f32_16x16x32_f16(ah[mt], bl, acc[mt][nt], 0, 0, 0);
      #pragma unroll
      for (int mt = 0; mt < 4; ++mt)
        acc[mt][nt] = __builtin_amdgcn_mfma_f32_16x16x32_f16(ah[mt], bh, acc[mt][nt], 0, 0, 0);
    }
    __builtin_amdgcn_sched_barrier(0);   // pin all reads/MFMAs before WAR barrier
    __builtin_amdgcn_s_barrier();        // all waves done reading sA/sB
    asm volatile("" ::: "memory");
    // stage next B-tile into the (now-free) single B buffer
    if (kt < 15) {
      #pragma unroll
      for (int l = 0; l < 4; ++l)
        GLOAD_LDS(bgp[l] + (size_t)(kt + 1) * 8192, sB + l * 4096 + wbase);
    }
    cur ^= 1;
  }
  // epilogue: scale by dis, fp16 round via LDS [128][136], coalesced store
  _Float16* sep = (_Float16*)smem;
  #pragma unroll
  for (int mt = 0; mt < 4; ++mt) {
    #pragma unroll
    for (int r = 0; r < 4; ++r) {
      int row = mbase + mt * 16 + quad * 4 + r;
      int gr = m0 + row;
      float dv = dis[gr < N ? gr : (N - 1)];
      #pragma unroll
      for (int nt = 0; nt < 4; ++nt) {
        int col = nbase + nt * 16 + lr;
        sep[row * 136 + col] = (_Float16)(acc[mt][nt][r] * dv);
      }
    }
  }
  __syncthreads();
  #pragma unroll
  for (int l = 0; l < 8; ++l) {
    int idx = l * 256 + tid;
    int row = idx >> 4;
    int c = (idx & 15) << 3;
    int gr = m0 + row;
    if (gr < N)
      *(uint4*)(hs + (size_t)gr * DHID + c) = *(uint4*)&sep[row * 136 + c];
  }
}

// ---------- fused agg1, unroll-8 gather for memory-level parallelism ----------
__global__ __launch_bounds__(256) void agg1_k(const __half* __restrict__ hs,
                                              const float* __restrict__ dis,
                                              const int* __restrict__ offs,
                                              const int* __restrict__ csr,
                                              const float* __restrict__ W2,
                                              const float* __restrict__ b1,
                                              float* __restrict__ gs, int N) {
  const int wid = threadIdx.x >> 6;
  const int lane = threadIdx.x & 63;
  const int i = blockIdx.x * 4 + wid;
  if (i >= N) return;
  const int f = lane * 2;
  const __half* hp = hs + f;   // lane-fixed column base
  float ax = 0.f, ay = 0.f;
  const int beg = offs[i], end = offs[i + 1];
  for (int base = beg; base < end; base += 64) {
    int sj = 0;
    if (base + lane < end) sj = csr[base + lane];  // coalesced edge-id load
    const int n = min(64, end - base);
    int t = 0;
    for (; t + 8 <= n; t += 8) {   // 8 independent gathers in flight
      int s0 = __shfl(sj, t + 0, 64), s1 = __shfl(sj, t + 1, 64);
      int s2 = __shfl(sj, t + 2, 64), s3 = __shfl(sj, t + 3, 64);
      int s4 = __shfl(sj, t + 4, 64), s5 = __shfl(sj, t + 5, 64);
      int s6 = __shfl(sj, t + 6, 64), s7 = __shfl(sj, t + 7, 64);
      __half2 h0 = *(const __half2*)(hp + (size_t)s0 * DHID);
      __half2 h1 = *(const __half2*)(hp + (size_t)s1 * DHID);
      __half2 h2 = *(const __half2*)(hp + (size_t)s2 * DHID);
      __half2 h3 = *(const __half2*)(hp + (size_t)s3 * DHID);
      __half2 h4 = *(const __half2*)(hp + (size_t)s4 * DHID);
      __half2 h5 = *(const __half2*)(hp + (size_t)s5 * DHID);
      __half2 h6 = *(const __half2*)(hp + (size_t)s6 * DHID);
      __half2 h7 = *(const __half2*)(hp + (size_t)s7 * DHID);
      float2 f0 = __half22float2(h0), f1 = __half22float2(h1);
      float2 f2 = __half22float2(h2), f3 = __half22float2(h3);
      float2 f4 = __half22float2(h4), f5 = __half22float2(h5);
      float2 f6 = __half22float2(h6), f7 = __half22float2(h7);
      ax += ((f0.x + f1.x) + (f2.x + f3.x)) + ((f4.x + f5.x) + (f6.x + f7.x));
      ay += ((f0.y + f1.y) + (f2.y + f3.y)) + ((f4.y + f5.y) + (f6.y + f7.y));
    }
    for (; t < n; ++t) {
      int s = __shfl(sj, t, 64);
      float2 hf = __half22float2(*(const __half2*)(hp + (size_t)s * DHID));
      ax += hf.x;
      ay += hf.y;
    }
  }
  {  // self-loop
    float2 hf = __half22float2(*(const __half2*)(hp + (size_t)i * DHID));
    ax += hf.x;
    ay += hf.y;
  }
  const float di = dis[i];
  float v0 = fmaxf(fmaf(ax, di, b1[f]), 0.f);
  float v1 = fmaxf(fmaf(ay, di, b1[f + 1]), 0.f);
  float p0 = fmaf(v0, W2[f * 4 + 0], v1 * W2[f * 4 + 4]);
  float p1 = fmaf(v0, W2[f * 4 + 1], v1 * W2[f * 4 + 5]);
  float p2 = fmaf(v0, W2[f * 4 + 2], v1 * W2[f * 4 + 6]);
  float p3 = fmaf(v0, W2[f * 4 + 3], v1 * W2[f * 4 + 7]);
  #pragma unroll
  for (int o = 32; o > 0; o >>= 1) {
    p0 += __shfl_xor(p0, o, 64);
    p1 += __shfl_xor(p1, o, 64);
    p2 += __shfl_xor(p2, o, 64);
    p3 += __shfl_xor(p3, o, 64);
  }
  if (lane == 0)
    *(float4*)(gs + (size_t)i * DOUT) = make_float4(p0 * di, p1 * di, p2 * di, p3 * di);
}

// ---------- layer-2: out = dis_i*(sum gs[s] + gs[i]) + b2, unroll-4 ----------
__global__ __launch_bounds__(256) void agg2_k(const float* __restrict__ gs,
                                              const float* __restrict__ dis,
                                              const int* __restrict__ offs,
                                              const int* __restrict__ csr,
                                              const float* __restrict__ b2,
                                              float* __restrict__ out, int N) {
  int i = blockIdx.x * 256 + threadIdx.x;
  if (i >= N) return;
  float a0 = 0.f, a1 = 0.f, a2 = 0.f, a3 = 0.f;
  const int beg = offs[i], end = offs[i + 1];
  int j = beg;
  for (; j + 4 <= end; j += 4) {
    int s0 = csr[j], s1 = csr[j + 1], s2 = csr[j + 2], s3 = csr[j + 3];
    float4 g0 = *(const float4*)(gs + (size_t)s0 * DOUT);
    float4 g1 = *(const float4*)(gs + (size_t)s1 * DOUT);
    float4 g2 = *(const float4*)(gs + (size_t)s2 * DOUT);
    float4 g3 = *(const float4*)(gs + (size_t)s3 * DOUT);
    a0 += (g0.x + g1.x) + (g2.x + g3.x);
    a1 += (g0.y + g1.y) + (g2.y + g3.y);
    a2 += (g0.z + g1.z) + (g2.z + g3.z);
    a3 += (g0.w + g1.w) + (g2.w + g3.w);
  }
  for (; j < end; ++j) {
    int s = csr[j];
    float4 gv = *(const float4*)(gs + (size_t)s * DOUT);
    a0 += gv.x; a1 += gv.y; a2 += gv.z; a3 += gv.w;
  }
  const float di = dis[i];
  float4 gi = *(const float4*)(gs + (size_t)i * DOUT);
  float4 o4;
  o4.x = fmaf(a0 + gi.x, di, b2[0]);
  o4.y = fmaf(a1 + gi.y, di, b2[1]);
  o4.z = fmaf(a2 + gi.z, di, b2[2]);
  o4.w = fmaf(a3 + gi.w, di, b2[3]);
  *(float4*)(out + (size_t)i * DOUT) = o4;
}

extern "C" void kernel_launch(void* const* d_in, const int* in_sizes, int n_in,
                              void* d_out, int out_size, void* d_ws, size_t ws_size,
                              hipStream_t stream) {
  const float* x  = (const float*)d_in[0];
  const int*   raw = (const int*)d_in[1];
  const float* W1 = (const float*)d_in[2];
  const float* b1 = (const float*)d_in[3];
  const float* W2 = (const float*)d_in[4];
  const float* b2 = (const float*)d_in[5];
  float* out = (float*)d_out;

  const int N = in_sizes[0] / DIN;   // 100000
  const int E = in_sizes[1] / 2;     // 3200000

  char* ws = (char*)d_ws;
  size_t off = 0;
  auto carve = [&](size_t bytes) -> char* {
    char* p = ws + off;
    off = (off + bytes + 255) & ~(size_t)255;
    return p;
  };
  float*    dis  = (float*)carve((size_t)N * 4);
  int*      offs = (int*)carve((size_t)(N + 1) * 4);
  int*      csr  = (int*)carve((size_t)E * 4);
  unsigned* pairs= (unsigned*)carve((size_t)E * 4);
  int*      boffs= (int*)carve(513 * 4);
  int*      bcur = (int*)carve(512 * 4);
  int*      gbcnt= (int*)carve(512 * 4);
  int*      flag = (int*)carve(256);
  __half*   Bt2  = (__half*)carve((size_t)DIN * DHID * 2 * 2);  // hi+lo tiled
  __half*   hs   = (__half*)carve((size_t)N * DHID * 2);
  float*    gs   = (float*)carve((size_t)N * DOUT * 4);
  (void)ws_size; (void)n_in; (void)out_size;

  const int gN = (N + 255) / 256;
  const int nbkt = (N + (1 << BSH) - 1) >> BSH;   // 391
  const int gA = (E + PA_CHUNK - 1) / PA_CHUNK;   // 391

  detect_i64_k<<<1, 64, 0, stream>>>(raw, flag);
  hipMemsetAsync(gbcnt, 0, 512 * 4, stream);
  bcount_k<<<gA, 256, 0, stream>>>(raw, flag, gbcnt, E);
  bscan_k<<<1, 512, 0, stream>>>(gbcnt, boffs, bcur, offs, nbkt, N, E);
  binA_k<<<gA, 256, 0, stream>>>(raw, flag, bcur, pairs, E);
  binB_k<<<nbkt, 256, 0, stream>>>(pairs, boffs, csr, offs, dis, N);
  wsplit_k<<<(DIN * DHID + 255) / 256, 256, 0, stream>>>(W1, Bt2);
  gemm1_k<<<(N + 127) / 128, 256, 0, stream>>>(x, Bt2, dis, hs, N);
  agg1_k<<<(N + 3) / 4, 256, 0, stream>>>(hs, dis, offs, csr, W2, b1, gs, N);
  agg2_k<<<gN, 256, 0, stream>>>(gs, dis, offs, csr, b2, out, N);
}

// Round 10
// 529.928 us; speedup vs baseline: 1.2952x; 1.0060x over previous
//
#include <hip/hip_runtime.h>
#include <hip/hip_fp16.h>

#define DIN 512
#define DHID 128
#define DOUT 4
#define BSH 8                 // bucket = 256 nodes
#define PA_CHUNK 8192         // edges per binning block (32/thread)

typedef _Float16 f16x8 __attribute__((ext_vector_type(8)));
typedef _Float16 f16x4 __attribute__((ext_vector_type(4)));
typedef float    f32x4 __attribute__((ext_vector_type(4)));

// async global->LDS DMA, 16B per lane (dest = wave-uniform base + lane*16)
#define GLOAD_LDS(gp, lp)                                                     \
  __builtin_amdgcn_global_load_lds(                                           \
      (const __attribute__((address_space(1))) void*)(gp),                    \
      (__attribute__((address_space(3))) void*)(lp), 16, 0, 0)

// ---------- fused: bcount (+inline i64 detect) | wsplit, role by blockIdx ----
// wsplit: W1 split to fp16 hi/lo, K-tiled LDS-linear layout
// Bt2[kt][row(n)][ hi kk=0..31 | lo kk=0..31 ]  (row = 128B, LDS-DMA-ready)
__global__ __launch_bounds__(256) void pre_k(const int* __restrict__ raw,
                                             const float* __restrict__ W1,
                                             int* __restrict__ gbcnt,
                                             __half* __restrict__ Bt2,
                                             int E, int gA) {
  if (blockIdx.x >= gA) {   // ---- wsplit role ----
    int idx = (blockIdx.x - gA) * 256 + threadIdx.x;   // 0..65535
    if (idx >= DIN * DHID) return;
    int k = idx >> 7;    // 0..511
    int n = idx & 127;
    int kt = k >> 5, kk = k & 31;
    float w = W1[idx];   // W1[k][n], coalesced read
    _Float16 hi = (_Float16)w;
    _Float16 lo = (_Float16)(w - (float)hi);
    size_t base = (size_t)(kt * 128 + n) * 64;
    Bt2[base + kk]      = *(__half*)&hi;
    Bt2[base + 32 + kk] = *(__half*)&lo;
    return;
  }
  // ---- bcount role ----
  __shared__ int h[512];
  __shared__ int sflag;
  const int tid = threadIdx.x;
  if (tid == 0) {
    int z = 1;
    for (int k = 0; k < 8; ++k)
      if (raw[2 * k + 1] != 0) z = 0;
    sflag = z;
  }
  for (int i = tid; i < 512; i += 256) h[i] = 0;
  __syncthreads();
  const int f = sflag;
  const size_t e0 = (size_t)blockIdx.x * PA_CHUNK;
  #pragma unroll
  for (int k = 0; k < 32; ++k) {
    size_t e = e0 + (size_t)k * 256 + tid;
    if (e < (size_t)E) {
      int d = f ? raw[2 * ((size_t)E + e)] : raw[(size_t)E + e];
      atomicAdd(&h[d >> BSH], 1);
    }
  }
  __syncthreads();
  for (int i = tid; i < 512; i += 256)
    if (h[i]) atomicAdd(&gbcnt[i], h[i]);
}

// ---------- bucket scan (single block) -> boffs, bcur; also offs[N]=E ----------
__global__ __launch_bounds__(512) void bscan_k(const int* __restrict__ gbcnt,
                                               int* __restrict__ boffs,
                                               int* __restrict__ bcur,
                                               int* __restrict__ offs,
                                               int nbkt, int N, int E) {
  __shared__ int sm[512];
  int t = threadIdx.x;
  int v = (t < nbkt) ? gbcnt[t] : 0;
  int x = v;
  sm[t] = x;
  __syncthreads();
  #pragma unroll
  for (int o = 1; o < 512; o <<= 1) {
    int y = (t >= o) ? sm[t - o] : 0;
    __syncthreads();
    x += y;
    sm[t] = x;
    __syncthreads();
  }
  if (t < nbkt) {
    boffs[t] = x - v;
    bcur[t] = x - v;
  }
  if (t == 0) {
    boffs[nbkt] = E;
    offs[N] = E;
  }
}

// ---------- binA: scatter packed (src<<8 | dst&255) into dst-bucket order ----
__global__ __launch_bounds__(256) void binA_k(const int* __restrict__ raw,
                                              int* __restrict__ bcur,
                                              unsigned* __restrict__ pairs, int E) {
  __shared__ int hist[512];
  __shared__ int base[512];
  __shared__ int sflag;
  const int tid = threadIdx.x;
  if (tid == 0) {
    int z = 1;
    for (int k = 0; k < 8; ++k)
      if (raw[2 * k + 1] != 0) z = 0;
    sflag = z;
  }
  for (int i = tid; i < 512; i += 256) hist[i] = 0;
  __syncthreads();
  const int f = sflag;
  const size_t e0 = (size_t)blockIdx.x * PA_CHUNK;
  int es[32], ed[32];
  #pragma unroll
  for (int k = 0; k < 32; ++k) {
    size_t e = e0 + (size_t)k * 256 + tid;
    if (e < (size_t)E) {
      es[k] = f ? raw[2 * e] : raw[e];
      ed[k] = f ? raw[2 * ((size_t)E + e)] : raw[(size_t)E + e];
      atomicAdd(&hist[ed[k] >> BSH], 1);
    } else {
      ed[k] = -1;
    }
  }
  __syncthreads();
  for (int i = tid; i < 512; i += 256) {
    int c = hist[i];
    base[i] = c ? atomicAdd(&bcur[i], c) : 0;
    hist[i] = 0;  // reuse as local cursor
  }
  __syncthreads();
  #pragma unroll
  for (int k = 0; k < 32; ++k) {
    if (ed[k] >= 0) {
      int b = ed[k] >> BSH;
      int pos = base[b] + atomicAdd(&hist[b], 1);
      pairs[pos] = ((unsigned)es[k] << 8) | ((unsigned)ed[k] & 255u);
    }
  }
}

// ---------- binB: per-bucket local count + scan -> offs/dis, then CSR fill ----
__global__ __launch_bounds__(256) void binB_k(const unsigned* __restrict__ pairs,
                                              const int* __restrict__ boffs,
                                              int* __restrict__ csr,
                                              int* __restrict__ offs,
                                              float* __restrict__ dis, int N) {
  __shared__ int lcnt[256];
  __shared__ int sc[256];
  const int tid = threadIdx.x;
  const int n0 = blockIdx.x << BSH;
  const int lo = boffs[blockIdx.x];
  const int hi = boffs[blockIdx.x + 1];
  lcnt[tid] = 0;
  __syncthreads();
  for (int j = lo + tid; j < hi; j += 256) atomicAdd(&lcnt[(int)(pairs[j] & 255u)], 1);
  __syncthreads();
  int v = lcnt[tid];
  int x = v;
  sc[tid] = x;
  __syncthreads();
  #pragma unroll
  for (int o = 1; o < 256; o <<= 1) {
    int y = (tid >= o) ? sc[tid - o] : 0;
    __syncthreads();
    x += y;
    sc[tid] = x;
    __syncthreads();
  }
  const int base = lo + x - v;   // node's CSR start
  const int node = n0 + tid;
  if (node < N) {
    offs[node] = base;
    dis[node] = rsqrtf((float)v + 1.0f);   // deg = in-degree + self-loop
  }
  __syncthreads();
  lcnt[tid] = base;   // reuse as cursor
  __syncthreads();
  for (int j = lo + tid; j < hi; j += 256) {
    unsigned p = pairs[j];
    int dl = (int)(p & 255u);
    int pos = atomicAdd(&lcnt[dl], 1);
    csr[pos] = (int)(p >> 8);   // lands in this bucket's span -> L2 absorbs
  }
}

// ---------- GEMM1 via split-fp16 MFMA: hs = fp16((X@W1) * dis) ----------
// Counted-vmcnt pipeline (round-8 measured best): A double-buffered via
// global_load_lds, next A-tile issued before compute, vmcnt(4) never 0 in
// steady state. B single-buffered, issued post-compute (L2-hot).
__global__ __launch_bounds__(256, 2) void gemm1_k(const float* __restrict__ A,
                                                  const __half* __restrict__ Bt2,
                                                  const float* __restrict__ dis,
                                                  __half* __restrict__ hs, int N) {
  __shared__ char smem[49152];   // Abuf0 16K | Abuf1 16K | Bbuf 16K
  char* const sB = smem + 32768;
  const int tid = threadIdx.x;
  const int wave = tid >> 6, lane = tid & 63;
  const int lr = lane & 15, quad = lane >> 4;
  const int m0 = blockIdx.x * 128;
  const int mbase = (wave >> 1) * 64;   // wave owns 64x64 of the 128x128 tile
  const int nbase = (wave & 1) * 64;
  const int wbase = (tid & ~63) * 16;   // wave-uniform LDS byte base per issue

  f32x4 acc[4][4];
  #pragma unroll
  for (int mt = 0; mt < 4; ++mt)
    #pragma unroll
    for (int nt = 0; nt < 4; ++nt) acc[mt][nt] = (f32x4){0.f, 0.f, 0.f, 0.f};

  // staging source geometry (dest16 = l*256 + tid); inverse swizzle on source
  const float*  agp[4];
  const __half* bgp[4];
  #pragma unroll
  for (int l = 0; l < 4; ++l) {
    int d16 = l * 256 + tid;
    int row = d16 >> 3;
    int chk = (d16 & 7) ^ (row & 7);
    int gr = m0 + row;
    if (gr >= N) gr = N - 1;            // clamp: dup data, rows >=N never stored
    agp[l] = A + (size_t)gr * DIN + chk * 4;
    bgp[l] = Bt2 + (size_t)row * 64 + chk * 8;
  }

  // prologue: stage tile 0 (A -> buf0, B -> sB); stays in flight into kt=0
  #pragma unroll
  for (int l = 0; l < 4; ++l)
    GLOAD_LDS(agp[l], smem + l * 4096 + wbase);
  #pragma unroll
  for (int l = 0; l < 4; ++l)
    GLOAD_LDS(bgp[l], sB + l * 4096 + wbase);

  int cur = 0;
  for (int kt = 0; kt < 16; ++kt) {
    // issue next A-tile into the other buffer; it rides across the barrier
    if (kt < 15) {
      char* dA = smem + (cur ^ 1) * 16384;
      #pragma unroll
      for (int l = 0; l < 4; ++l)
        GLOAD_LDS(agp[l] + (kt + 1) * 32, dA + l * 4096 + wbase);
      asm volatile("s_waitcnt vmcnt(4)" ::: "memory");   // tile kt (A+B) landed
    } else {
      asm volatile("s_waitcnt vmcnt(0)" ::: "memory");   // final drain
    }
    __builtin_amdgcn_s_barrier();        // all waves' tile-kt data visible
    asm volatile("" ::: "memory");
    // ---- compute tile kt: swizzled ds_read + in-register fp32->hi/lo ----
    char* sA = smem + cur * 16384;
    f16x8 ah[4], al[4];
    #pragma unroll
    for (int mt = 0; mt < 4; ++mt) {
      int r = mbase + mt * 16 + lr;
      f32x4 v0 = *(const f32x4*)(sA + r * 128 + (((2 * quad + 0) ^ (r & 7)) << 4));
      f32x4 v1 = *(const f32x4*)(sA + r * 128 + (((2 * quad + 1) ^ (r & 7)) << 4));
      _Float16 c0 = (_Float16)v0[0], c1 = (_Float16)v0[1],
               c2 = (_Float16)v0[2], c3 = (_Float16)v0[3],
               c4 = (_Float16)v1[0], c5 = (_Float16)v1[1],
               c6 = (_Float16)v1[2], c7 = (_Float16)v1[3];
      ah[mt] = (f16x8){c0, c1, c2, c3, c4, c5, c6, c7};
      al[mt] = (f16x8){(_Float16)(v0[0] - (float)c0), (_Float16)(v0[1] - (float)c1),
                       (_Float16)(v0[2] - (float)c2), (_Float16)(v0[3] - (float)c3),
                       (_Float16)(v1[0] - (float)c4), (_Float16)(v1[1] - (float)c5),
                       (_Float16)(v1[2] - (float)c6), (_Float16)(v1[3] - (float)c7)};
    }
    #pragma unroll
    for (int nt = 0; nt < 4; ++nt) {
      int c = nbase + nt * 16 + lr;
      f16x8 bh = *(const f16x8*)(sB + c * 128 + (((0 + quad) ^ (c & 7)) << 4));
      f16x8 bl = *(const f16x8*)(sB + c * 128 + (((4 + quad) ^ (c & 7)) << 4));
      #pragma unroll
      for (int mt = 0; mt < 4; ++mt)
        acc[mt][nt] = __builtin_amdgcn_mfma_f32_16x16x32_f16(al[mt], bh, acc[mt][nt], 0, 0, 0);
      #pragma unroll
      for (int mt = 0; mt < 4; ++mt)
        acc[mt][nt] = __builtin_amdgcn_mfma_f32_16x16x32_f16(ah[mt], bl, acc[mt][nt], 0, 0, 0);
      #pragma unroll
      for (int mt = 0; mt < 4; ++mt)
        acc[mt][nt] = __builtin_amdgcn_mfma_f32_16x16x32_f16(ah[mt], bh, acc[mt][nt], 0, 0, 0);
    }
    __builtin_amdgcn_sched_barrier(0);   // pin all reads/MFMAs before WAR barrier
    __builtin_amdgcn_s_barrier();        // all waves done reading sA/sB
    asm volatile("" ::: "memory");
    // stage next B-tile into the (now-free) single B buffer
    if (kt < 15) {
      #pragma unroll
      for (int l = 0; l < 4; ++l)
        GLOAD_LDS(bgp[l] + (size_t)(kt + 1) * 8192, sB + l * 4096 + wbase);
    }
    cur ^= 1;
  }
  // epilogue: scale by dis, fp16 round via LDS [128][136], coalesced store
  _Float16* sep = (_Float16*)smem;
  #pragma unroll
  for (int mt = 0; mt < 4; ++mt) {
    #pragma unroll
    for (int r = 0; r < 4; ++r) {
      int row = mbase + mt * 16 + quad * 4 + r;
      int gr = m0 + row;
      float dv = dis[gr < N ? gr : (N - 1)];
      #pragma unroll
      for (int nt = 0; nt < 4; ++nt) {
        int col = nbase + nt * 16 + lr;
        sep[row * 136 + col] = (_Float16)(acc[mt][nt][r] * dv);
      }
    }
  }
  __syncthreads();
  #pragma unroll
  for (int l = 0; l < 8; ++l) {
    int idx = l * 256 + tid;
    int row = idx >> 4;
    int c = (idx & 15) << 3;
    int gr = m0 + row;
    if (gr < N)
      *(uint4*)(hs + (size_t)gr * DHID + c) = *(uint4*)&sep[row * 136 + c];
  }
}

// ---------- fused agg1: pair-gather (2 edges / load, 512B per VMEM instr) ----
// Lane layout: half = lane>>5 picks the edge of a pair; li = lane&31 covers
// 4 columns (short4 = 8B). Tail shfl executed by ALL lanes (ds_bpermute from
// an inactive source lane is undefined on CDNA — round-9 bug).
__global__ __launch_bounds__(256) void agg1_k(const __half* __restrict__ hs,
                                              const float* __restrict__ dis,
                                              const int* __restrict__ offs,
                                              const int* __restrict__ csr,
                                              const float* __restrict__ W2,
                                              const float* __restrict__ b1,
                                              float* __restrict__ gs, int N) {
  const int wid = threadIdx.x >> 6;
  const int lane = threadIdx.x & 63;
  const int i = blockIdx.x * 4 + wid;
  if (i >= N) return;
  const int half = lane >> 5;
  const int li = lane & 31;
  const __half* hp = hs + li * 4;   // lane-fixed 4-column base
  float a0 = 0.f, a1 = 0.f, a2 = 0.f, a3 = 0.f;
  const int beg = offs[i], end = offs[i + 1];
  for (int base = beg; base < end; base += 64) {
    int sj = 0;
    if (base + lane < end) sj = csr[base + lane];  // coalesced edge-id load
    const int n = min(64, end - base);
    int t = 0;
    for (; t + 16 <= n; t += 16) {   // 8 paired loads = 16 edges in flight
      int s0 = __shfl(sj, t + 0  + half, 64);
      int s1 = __shfl(sj, t + 2  + half, 64);
      int s2 = __shfl(sj, t + 4  + half, 64);
      int s3 = __shfl(sj, t + 6  + half, 64);
      int s4 = __shfl(sj, t + 8  + half, 64);
      int s5 = __shfl(sj, t + 10 + half, 64);
      int s6 = __shfl(sj, t + 12 + half, 64);
      int s7 = __shfl(sj, t + 14 + half, 64);
      short4 h0 = *(const short4*)(hp + (size_t)s0 * DHID);
      short4 h1 = *(const short4*)(hp + (size_t)s1 * DHID);
      short4 h2 = *(const short4*)(hp + (size_t)s2 * DHID);
      short4 h3 = *(const short4*)(hp + (size_t)s3 * DHID);
      short4 h4 = *(const short4*)(hp + (size_t)s4 * DHID);
      short4 h5 = *(const short4*)(hp + (size_t)s5 * DHID);
      short4 h6 = *(const short4*)(hp + (size_t)s6 * DHID);
      short4 h7 = *(const short4*)(hp + (size_t)s7 * DHID);
      #define ACC4(hv)                                                         \
      {                                                                        \
        float2 fa = __half22float2(*(const __half2*)&(hv).x);                  \
        float2 fb = __half22float2(*(const __half2*)&(hv).z);                  \
        a0 += fa.x; a1 += fa.y; a2 += fb.x; a3 += fb.y;                        \
      }
      ACC4(h0) ACC4(h1) ACC4(h2) ACC4(h3)
      ACC4(h4) ACC4(h5) ACC4(h6) ACC4(h7)
      #undef ACC4
    }
    for (; t < n; t += 2) {          // tail: pair (t, t+1), guard odd
      int e = t + half;
      bool ok = e < n;
      int s = __shfl(sj, ok ? e : 0, 64);   // ALL lanes execute the shfl
      if (ok) {
        short4 hv = *(const short4*)(hp + (size_t)s * DHID);
        float2 fa = __half22float2(*(const __half2*)&hv.x);
        float2 fb = __half22float2(*(const __half2*)&hv.z);
        a0 += fa.x; a1 += fa.y; a2 += fb.x; a3 += fb.y;
      }
    }
  }
  // combine edge-parity halves (lane l and l+32 cover the same 4 columns)
  a0 += __shfl_xor(a0, 32, 64);
  a1 += __shfl_xor(a1, 32, 64);
  a2 += __shfl_xor(a2, 32, 64);
  a3 += __shfl_xor(a3, 32, 64);
  {  // self-loop (all lanes; both halves add the same value consistently)
    short4 hv = *(const short4*)(hp + (size_t)i * DHID);
    float2 fa = __half22float2(*(const __half2*)&hv.x);
    float2 fb = __half22float2(*(const __half2*)&hv.z);
    a0 += fa.x; a1 += fa.y; a2 += fb.x; a3 += fb.y;
  }
  const float di = dis[i];
  float4 bv = *(const float4*)(b1 + li * 4);
  float v0 = fmaxf(fmaf(a0, di, bv.x), 0.f);
  float v1 = fmaxf(fmaf(a1, di, bv.y), 0.f);
  float v2 = fmaxf(fmaf(a2, di, bv.z), 0.f);
  float v3 = fmaxf(fmaf(a3, di, bv.w), 0.f);
  float4 w0 = *(const float4*)(W2 + (size_t)(li * 4 + 0) * 4);
  float4 w1 = *(const float4*)(W2 + (size_t)(li * 4 + 1) * 4);
  float4 w2 = *(const float4*)(W2 + (size_t)(li * 4 + 2) * 4);
  float4 w3 = *(const float4*)(W2 + (size_t)(li * 4 + 3) * 4);
  float p0 = fmaf(v0, w0.x, fmaf(v1, w1.x, fmaf(v2, w2.x, v3 * w3.x)));
  float p1 = fmaf(v0, w0.y, fmaf(v1, w1.y, fmaf(v2, w2.y, v3 * w3.y)));
  float p2 = fmaf(v0, w0.z, fmaf(v1, w1.z, fmaf(v2, w2.z, v3 * w3.z)));
  float p3 = fmaf(v0, w0.w, fmaf(v1, w1.w, fmaf(v2, w2.w, v3 * w3.w)));
  #pragma unroll
  for (int o = 16; o > 0; o >>= 1) {   // reduce within each 32-lane half
    p0 += __shfl_xor(p0, o, 64);
    p1 += __shfl_xor(p1, o, 64);
    p2 += __shfl_xor(p2, o, 64);
    p3 += __shfl_xor(p3, o, 64);
  }
  if (lane == 0)
    *(float4*)(gs + (size_t)i * DOUT) = make_float4(p0 * di, p1 * di, p2 * di, p3 * di);
}

// ---------- layer-2: out = dis_i*(sum gs[s] + gs[i]) + b2, unroll-4 ----------
__global__ __launch_bounds__(256) void agg2_k(const float* __restrict__ gs,
                                              const float* __restrict__ dis,
                                              const int* __restrict__ offs,
                                              const int* __restrict__ csr,
                                              const float* __restrict__ b2,
                                              float* __restrict__ out, int N) {
  int i = blockIdx.x * 256 + threadIdx.x;
  if (i >= N) return;
  float a0 = 0.f, a1 = 0.f, a2 = 0.f, a3 = 0.f;
  const int beg = offs[i], end = offs[i + 1];
  int j = beg;
  for (; j + 4 <= end; j += 4) {
    int s0 = csr[j], s1 = csr[j + 1], s2 = csr[j + 2], s3 = csr[j + 3];
    float4 g0 = *(const float4*)(gs + (size_t)s0 * DOUT);
    float4 g1 = *(const float4*)(gs + (size_t)s1 * DOUT);
    float4 g2 = *(const float4*)(gs + (size_t)s2 * DOUT);
    float4 g3 = *(const float4*)(gs + (size_t)s3 * DOUT);
    a0 += (g0.x + g1.x) + (g2.x + g3.x);
    a1 += (g0.y + g1.y) + (g2.y + g3.y);
    a2 += (g0.z + g1.z) + (g2.z + g3.z);
    a3 += (g0.w + g1.w) + (g2.w + g3.w);
  }
  for (; j < end; ++j) {
    int s = csr[j];
    float4 gv = *(const float4*)(gs + (size_t)s * DOUT);
    a0 += gv.x; a1 += gv.y; a2 += gv.z; a3 += gv.w;
  }
  const float di = dis[i];
  float4 gi = *(const float4*)(gs + (size_t)i * DOUT);
  float4 o4;
  o4.x = fmaf(a0 + gi.x, di, b2[0]);
  o4.y = fmaf(a1 + gi.y, di, b2[1]);
  o4.z = fmaf(a2 + gi.z, di, b2[2]);
  o4.w = fmaf(a3 + gi.w, di, b2[3]);
  *(float4*)(out + (size_t)i * DOUT) = o4;
}

extern "C" void kernel_launch(void* const* d_in, const int* in_sizes, int n_in,
                              void* d_out, int out_size, void* d_ws, size_t ws_size,
                              hipStream_t stream) {
  const float* x  = (const float*)d_in[0];
  const int*   raw = (const int*)d_in[1];
  const float* W1 = (const float*)d_in[2];
  const float* b1 = (const float*)d_in[3];
  const float* W2 = (const float*)d_in[4];
  const float* b2 = (const float*)d_in[5];
  float* out = (float*)d_out;

  const int N = in_sizes[0] / DIN;   // 100000
  const int E = in_sizes[1] / 2;     // 3200000

  char* ws = (char*)d_ws;
  size_t off = 0;
  auto carve = [&](size_t bytes) -> char* {
    char* p = ws + off;
    off = (off + bytes + 255) & ~(size_t)255;
    return p;
  };
  float*    dis  = (float*)carve((size_t)N * 4);
  int*      offs = (int*)carve((size_t)(N + 1) * 4);
  int*      csr  = (int*)carve((size_t)E * 4);
  unsigned* pairs= (unsigned*)carve((size_t)E * 4);
  int*      boffs= (int*)carve(513 * 4);
  int*      bcur = (int*)carve(512 * 4);
  int*      gbcnt= (int*)carve(512 * 4);
  __half*   Bt2  = (__half*)carve((size_t)DIN * DHID * 2 * 2);  // hi+lo tiled
  __half*   hs   = (__half*)carve((size_t)N * DHID * 2);
  float*    gs   = (float*)carve((size_t)N * DOUT * 4);
  (void)ws_size; (void)n_in; (void)out_size;

  const int gN = (N + 255) / 256;
  const int nbkt = (N + (1 << BSH) - 1) >> BSH;   // 391
  const int gA = (E + PA_CHUNK - 1) / PA_CHUNK;   // 391
  const int gW = (DIN * DHID + 255) / 256;        // 256 wsplit blocks

  hipMemsetAsync(gbcnt, 0, 512 * 4, stream);
  pre_k<<<gA + gW, 256, 0, stream>>>(raw, W1, gbcnt, Bt2, E, gA);
  bscan_k<<<1, 512, 0, stream>>>(gbcnt, boffs, bcur, offs, nbkt, N, E);
  binA_k<<<gA, 256, 0, stream>>>(raw, bcur, pairs, E);
  binB_k<<<nbkt, 256, 0, stream>>>(pairs, boffs, csr, offs, dis, N);
  gemm1_k<<<(N + 127) / 128, 256, 0, stream>>>(x, Bt2, dis, hs, N);
  agg1_k<<<(N + 3) / 4, 256, 0, stream>>>(hs, dis, offs, csr, W2, b1, gs, N);
  agg2_k<<<gN, 256, 0, stream>>>(gs, dis, offs, csr, b2, out, N);
}